// Round 1
// baseline (581.695 us; speedup 1.0000x reference)
//
#include <hip/hip_runtime.h>
#include <math.h>

#define BB   8
#define SQ   16
#define HIDD 1024
#define NHD  16
#define PAST 4096
#define DH   64
#define SKV  (PAST + SQ)    // 4112
#define NTOK (BB * SQ)      // 128

// ---------------------------------------------------------------------------
// gemm3: C = A(128xK=1024) @ W(1024x1024) + bias, three weight slots selected
// by blockIdx.x>>4. BM=32, BN=64, BK=32, 256 threads, 2x4 micro-tile.
// ---------------------------------------------------------------------------
__global__ __launch_bounds__(256) void gemm3(
    const float* __restrict__ A,
    const float* __restrict__ W0, const float* __restrict__ W1, const float* __restrict__ W2,
    const float* __restrict__ b0, const float* __restrict__ b1, const float* __restrict__ b2,
    float* __restrict__ O0, float* __restrict__ O1, float* __restrict__ O2)
{
    const int nt   = blockIdx.x;
    const int mt   = blockIdx.y;
    const int wsel = nt >> 4;
    const int col0 = (nt & 15) * 64;
    const int m0   = mt * 32;
    const float* W    = (wsel == 0) ? W0 : (wsel == 1) ? W1 : W2;
    const float* bias = (wsel == 0) ? b0 : (wsel == 1) ? b1 : b2;
    float*       Out  = (wsel == 0) ? O0 : (wsel == 1) ? O1 : O2;

    __shared__ float As[32][33];   // +1 pad
    __shared__ float Bs[32][64];

    const int t    = threadIdx.x;
    const int tm   = t >> 4;          // 0..15 -> rows 2tm,2tm+1
    const int tn   = t & 15;          // cols 4tn..4tn+3
    const int arow = t >> 3;          // 0..31
    const int acol = (t & 7) << 2;    // 0..28
    const int brow = t >> 4;          // 0..15
    const int bcol = (t & 15) << 2;   // 0..60

    float acc0[4] = {0.f,0.f,0.f,0.f};
    float acc1[4] = {0.f,0.f,0.f,0.f};

    for (int k0 = 0; k0 < HIDD; k0 += 32) {
        __syncthreads();
        float4 a4 = *(const float4*)(A + (size_t)(m0 + arow) * HIDD + k0 + acol);
        As[arow][acol+0] = a4.x; As[arow][acol+1] = a4.y;
        As[arow][acol+2] = a4.z; As[arow][acol+3] = a4.w;
        *(float4*)(&Bs[brow][bcol]) =
            *(const float4*)(W + (size_t)(k0 + brow) * HIDD + col0 + bcol);
        *(float4*)(&Bs[brow + 16][bcol]) =
            *(const float4*)(W + (size_t)(k0 + brow + 16) * HIDD + col0 + bcol);
        __syncthreads();
        #pragma unroll
        for (int kk = 0; kk < 32; ++kk) {
            const float  a0 = As[2*tm][kk];
            const float  a1 = As[2*tm + 1][kk];
            const float4 b4 = *(const float4*)(&Bs[kk][tn << 2]);
            acc0[0] += a0*b4.x; acc0[1] += a0*b4.y; acc0[2] += a0*b4.z; acc0[3] += a0*b4.w;
            acc1[0] += a1*b4.x; acc1[1] += a1*b4.y; acc1[2] += a1*b4.z; acc1[3] += a1*b4.w;
        }
    }
    const float4 bb = *(const float4*)(bias + col0 + (tn << 2));
    float* o0 = Out + (size_t)(m0 + 2*tm) * HIDD + col0 + (tn << 2);
    float* o1 = o0 + HIDD;
    o0[0] = acc0[0] + bb.x; o0[1] = acc0[1] + bb.y; o0[2] = acc0[2] + bb.z; o0[3] = acc0[3] + bb.w;
    o1[0] = acc1[0] + bb.x; o1[1] = acc1[1] + bb.y; o1[2] = acc1[2] + bb.z; o1[3] = acc1[3] + bb.w;
}

// ---------------------------------------------------------------------------
// rope_scatter: RoPE over full 1024-dim rows (half = 512, per reference), then
// scatter to head layouts. Q -> ws (B,NH,SQ,DH); K,V -> tails of new_key/new_value.
// ---------------------------------------------------------------------------
__global__ __launch_bounds__(256) void rope_scatter(
    const float* __restrict__ qr, const float* __restrict__ kr, const float* __restrict__ vr,
    const int* __restrict__ pos_ids,
    float* __restrict__ Qh, float* __restrict__ nk, float* __restrict__ nv)
{
    const int tok = blockIdx.x;         // 0..127
    const int b   = tok >> 4;
    const int s   = tok & 15;
    const float pos = (float)pos_ids[tok];
    const size_t rq = (size_t)tok * HIDD;
    for (int i = threadIdx.x; i < 512; i += 256) {
        const float inv = expf((float)i * (-9.210340371976184f / 512.0f)); // 1/10000^(i/512)
        const float ang = pos * inv;
        const float c  = cosf(ang);
        const float sn = sinf(ang);
        const int h1 = i >> 6, d = i & 63;
        const int h2 = h1 + 8;           // (i+512)>>6
        float x1, x2;
        x1 = qr[rq + i]; x2 = qr[rq + i + 512];
        Qh[((size_t)(b*NHD + h1)*SQ + s)*DH + d] = x1*c - x2*sn;
        Qh[((size_t)(b*NHD + h2)*SQ + s)*DH + d] = x2*c + x1*sn;
        x1 = kr[rq + i]; x2 = kr[rq + i + 512];
        nk[((size_t)(b*NHD + h1)*SKV + PAST + s)*DH + d] = x1*c - x2*sn;
        nk[((size_t)(b*NHD + h2)*SKV + PAST + s)*DH + d] = x2*c + x1*sn;
        x1 = vr[rq + i]; x2 = vr[rq + i + 512];
        nv[((size_t)(b*NHD + h1)*SKV + PAST + s)*DH + d] = x1;
        nv[((size_t)(b*NHD + h2)*SKV + PAST + s)*DH + d] = x2;
    }
}

// ---------------------------------------------------------------------------
// attn_partial: fused past->new KV copy + flash-style partial attention.
// grid = (8 chunks of 512 keys, 128 (b,h)). 256 threads = 4 waves.
// Wave w owns queries 4w..4w+3. Scores: lane<->key (XOR-swizzled K tile so
// per-lane b128 row reads are conflict-free). PV: lane = (q in wave, d/4).
// Chunk 7 appends the 16 new keys (+ attention_mask).
// LDS = 4 + 16 + 16 + 4 KB = 40960 B exactly -> 4 blocks/CU.
// ---------------------------------------------------------------------------
__global__ __launch_bounds__(256) void attn_partial(
    const float* __restrict__ pk, const float* __restrict__ pv,
    const float* __restrict__ Qh, const float* __restrict__ amask,
    float* __restrict__ nk, float* __restrict__ nv,
    float* __restrict__ pc, float* __restrict__ pm, float* __restrict__ pl)
{
    const int chunk = blockIdx.x;   // 0..7
    const int bh    = blockIdx.y;   // 0..127
    const int b     = bh >> 4;
    const int t     = threadIdx.x;
    const int w     = t >> 6;       // wave 0..3
    const int lane  = t & 63;
    const int qq    = lane >> 4;    // query within wave (PV layout)
    const int d4    = lane & 15;    // float4 index of d (PV layout)

    __shared__ float  Qs[SQ * DH];      // pre-scaled Q (16x64)
    __shared__ float4 Ks[64 * 16];      // swizzled K tile
    __shared__ float  Vs[64 * DH];      // plain V tile
    __shared__ float4 Ps[4 * 64];       // per-wave P: [w][key] = {p_q0..p_q3}

    // stage Q, folding in the 1/sqrt(dh) scale
    {
        const int q = t >> 4, i = t & 15;
        float4 q4 = *(const float4*)(Qh + ((size_t)bh * SQ + q) * DH + 4*i);
        q4.x *= 0.125f; q4.y *= 0.125f; q4.z *= 0.125f; q4.w *= 0.125f;
        *(float4*)(&Qs[q * DH + 4*i]) = q4;
    }

    float m_r[4], l_r[4];
    #pragma unroll
    for (int q = 0; q < 4; ++q) { m_r[q] = -3.0e38f; l_r[q] = 0.0f; }
    float4 ctx = make_float4(0.f, 0.f, 0.f, 0.f);

    const int ntiles = (chunk == 7) ? 9 : 8;
    for (int tile = 0; tile < ntiles; ++tile) {
        __syncthreads();   // protect LDS reuse from previous iteration
        if (tile < 8) {
            const int k0 = chunk * 512 + tile * 64;
            #pragma unroll
            for (int p = 0; p < 4; ++p) {
                const int c = t + 256 * p;       // 0..1023
                const int j = c >> 4, i = c & 15;
                const size_t po = ((size_t)bh * PAST + k0 + j) * DH + 4*i;
                const size_t no = ((size_t)bh * SKV  + k0 + j) * DH + 4*i;
                const float4 k4 = *(const float4*)(pk + po);
                *(float4*)(nk + no) = k4;                 // fused copy
                Ks[j * 16 + (i ^ (j & 7))] = k4;          // swizzled stage
                const float4 v4 = *(const float4*)(pv + po);
                *(float4*)(nv + no) = v4;                 // fused copy
                *(float4*)(&Vs[j * DH + 4*i]) = v4;
            }
        } else {
            // 16 new keys, already rope'd + written to tails by rope_scatter
            const int j = t >> 4, i = t & 15;
            const size_t no = ((size_t)bh * SKV + PAST + j) * DH + 4*i;
            Ks[j * 16 + (i ^ (j & 7))] = *(const float4*)(nk + no);
            *(float4*)(&Vs[j * DH + 4*i]) = *(const float4*)(nv + no);
        }
        __syncthreads();

        const int jcount = (tile < 8) ? 64 : 16;

        // ---- scores: lane = key, 4 queries per wave ----
        float s[4];
        {
            float4 acc[4];
            #pragma unroll
            for (int q = 0; q < 4; ++q) acc[q] = make_float4(0.f,0.f,0.f,0.f);
            if (lane < jcount) {
                #pragma unroll
                for (int i = 0; i < 16; ++i) {
                    const float4 k4 = Ks[lane * 16 + (i ^ (lane & 7))];
                    #pragma unroll
                    for (int q = 0; q < 4; ++q) {
                        const float4 q4 = *(const float4*)(&Qs[(4*w + q) * DH + 4*i]);
                        acc[q].x += k4.x * q4.x; acc[q].y += k4.y * q4.y;
                        acc[q].z += k4.z * q4.z; acc[q].w += k4.w * q4.w;
                    }
                }
            }
            #pragma unroll
            for (int q = 0; q < 4; ++q)
                s[q] = (lane < jcount) ? (acc[q].x + acc[q].y + acc[q].z + acc[q].w)
                                       : -3.0e38f;
        }
        if (tile == 8 && lane < 16) {
            #pragma unroll
            for (int q = 0; q < 4; ++q)
                s[q] += amask[((size_t)b * SQ + 4*w + q) * SQ + lane];
        }

        // ---- online softmax per wave ----
        float alpha[4], pjv[4];
        #pragma unroll
        for (int q = 0; q < 4; ++q) {
            float mx = s[q];
            #pragma unroll
            for (int off = 1; off < 64; off <<= 1)
                mx = fmaxf(mx, __shfl_xor(mx, off, 64));
            const float mnew = fmaxf(m_r[q], mx);
            alpha[q] = __expf(m_r[q] - mnew);
            const float p = __expf(s[q] - mnew);
            pjv[q] = p;
            float ps = p;
            #pragma unroll
            for (int off = 1; off < 64; off <<= 1)
                ps += __shfl_xor(ps, off, 64);
            l_r[q] = l_r[q] * alpha[q] + ps;
            m_r[q] = mnew;
        }
        {
            float4 pw;
            pw.x = pjv[0]; pw.y = pjv[1]; pw.z = pjv[2]; pw.w = pjv[3];
            Ps[w * 64 + lane] = pw;   // per-wave private; same-wave in-order DS
        }

        // rescale ctx by alpha of this lane's query
        const float asel = (qq == 0) ? alpha[0] : (qq == 1) ? alpha[1]
                         : (qq == 2) ? alpha[2] : alpha[3];
        ctx.x *= asel; ctx.y *= asel; ctx.z *= asel; ctx.w *= asel;

        // ---- PV: lane = (qq, d4) ----
        const float* Pf = (const float*)&Ps[w * 64];
        for (int j = 0; j < jcount; ++j) {
            const float  p  = Pf[4*j + qq];
            const float4 v4 = *(const float4*)(&Vs[j * DH + 4*d4]);
            ctx.x += p * v4.x; ctx.y += p * v4.y; ctx.z += p * v4.z; ctx.w += p * v4.w;
        }
    }

    // write partials (unnormalized ctx + m,l)
    const int blk = bh * 8 + chunk;
    const int qg  = 4*w + qq;
    *(float4*)(pc + (size_t)blk * 1024 + qg * DH + 4*d4) = ctx;
    if (d4 == 0) {
        const float msel = (qq == 0) ? m_r[0] : (qq == 1) ? m_r[1] : (qq == 2) ? m_r[2] : m_r[3];
        const float lsel = (qq == 0) ? l_r[0] : (qq == 1) ? l_r[1] : (qq == 2) ? l_r[2] : l_r[3];
        pm[blk * 16 + qg] = msel;
        pl[blk * 16 + qg] = lsel;
    }
}

// ---------------------------------------------------------------------------
// attn_reduce: merge 8 chunk-partials per (b,h), normalize, write ctx in
// (token, hid) layout for the output projection.
// ---------------------------------------------------------------------------
__global__ __launch_bounds__(256) void attn_reduce(
    const float* __restrict__ pc, const float* __restrict__ pm,
    const float* __restrict__ pl, float* __restrict__ ctxw)
{
    const int bh = blockIdx.x;
    const int b  = bh >> 4, h = bh & 15;
    const int t  = threadIdx.x;
    __shared__ float mg[SQ], li[SQ];
    if (t < SQ) {
        float m = -3.0e38f;
        #pragma unroll
        for (int c = 0; c < 8; ++c) m = fmaxf(m, pm[(bh*8 + c) * 16 + t]);
        float L = 0.f;
        #pragma unroll
        for (int c = 0; c < 8; ++c)
            L += pl[(bh*8 + c) * 16 + t] * __expf(pm[(bh*8 + c) * 16 + t] - m);
        mg[t] = m; li[t] = 1.0f / L;
    }
    __syncthreads();
    #pragma unroll
    for (int r = 0; r < 4; ++r) {
        const int idx = t + 256 * r;          // (q,d) in 0..1023
        const int q = idx >> 6, d = idx & 63;
        float acc = 0.f;
        #pragma unroll
        for (int c = 0; c < 8; ++c)
            acc += pc[(size_t)(bh*8 + c) * 1024 + idx]
                 * __expf(pm[(bh*8 + c) * 16 + q] - mg[q]);
        ctxw[((size_t)(b*SQ + q) * NHD + h) * DH + d] = acc * li[q];
    }
}

// ---------------------------------------------------------------------------
extern "C" void kernel_launch(void* const* d_in, const int* in_sizes, int n_in,
                              void* d_out, int out_size, void* d_ws, size_t ws_size,
                              hipStream_t stream)
{
    const float* hidden = (const float*)d_in[0];
    const float* amask  = (const float*)d_in[1];
    const float* past_k = (const float*)d_in[2];
    const float* past_v = (const float*)d_in[3];
    const int*   pos    = (const int*)  d_in[4];
    const float* Wq = (const float*)d_in[5];  const float* bq = (const float*)d_in[6];
    const float* Wk = (const float*)d_in[7];  const float* bk = (const float*)d_in[8];
    const float* Wv = (const float*)d_in[9];  const float* bv = (const float*)d_in[10];
    const float* Wo = (const float*)d_in[11]; const float* bo = (const float*)d_in[12];

    float* out = (float*)d_out;                       // (128,1024)
    float* nk  = out + (size_t)NTOK * HIDD;           // (8,16,4112,64)
    float* nv  = nk + (size_t)BB * NHD * SKV * DH;    // (8,16,4112,64)

    // workspace layout (floats): ~6.95 MB total
    float* ws     = (float*)d_ws;
    float* q_raw  = ws;                        // 131072
    float* k_raw  = q_raw + 131072;            // 131072
    float* v_raw  = k_raw + 131072;            // 131072
    float* Qh     = v_raw + 131072;            // 131072 (B,NH,SQ,DH)
    float* pc     = Qh    + 131072;            // 1024*1024 ctx partials
    float* pm     = pc    + 1024 * 1024;       // 1024*16
    float* pl     = pm    + 1024 * 16;         // 1024*16
    float* ctxw   = pl    + 1024 * 16;         // 131072

    // 1) QKV projections
    gemm3<<<dim3(48, 4), 256, 0, stream>>>(hidden, Wq, Wk, Wv, bq, bk, bv,
                                           q_raw, k_raw, v_raw);
    // 2) RoPE + scatter (+ new_key/new_value tails)
    rope_scatter<<<NTOK, 256, 0, stream>>>(q_raw, k_raw, v_raw, pos, Qh, nk, nv);
    // 3) fused KV copy + partial attention
    attn_partial<<<dim3(8, 128), 256, 0, stream>>>(past_k, past_v, Qh, amask,
                                                   nk, nv, pc, pm, pl);
    // 4) merge partials -> ctx (token, hid)
    attn_reduce<<<128, 256, 0, stream>>>(pc, pm, pl, ctxw);
    // 5) output projection
    gemm3<<<dim3(16, 4), 256, 0, stream>>>(ctxw, Wo, Wo, Wo, bo, bo, bo,
                                           out, out, out);
}